// Round 1
// baseline (216.227 us; speedup 1.0000x reference)
//
#include <hip/hip_runtime.h>

// out = x + 42.0f over 33,554,432 fp32. Memory-bound streaming kernel.
// 268 MB compulsory traffic; floor ~42.6 us @ 6.3 TB/s achievable.
// MLP=4: four independent 16B vectors in flight per thread before any store,
// 8,192 blocks (half of previous) to cut dispatch overhead. Nontemporal
// load/store hints kept: stream is 8x aggregate L2, zero reuse, so avoiding
// L2 write-allocate pollution is strictly correct.
// NOTE: __builtin_nontemporal_* rejects HIP's float4 struct; use a native
// clang ext_vector_type, same 16B layout.

typedef float floatx4 __attribute__((ext_vector_type(4)));

__global__ __launch_bounds__(256) void add42_kernel(
    const floatx4* __restrict__ x, floatx4* __restrict__ out, int n4) {
    int base = blockIdx.x * (blockDim.x * 4) + threadIdx.x;
    int i0 = base;
    int i1 = base + blockDim.x;
    int i2 = base + 2 * blockDim.x;
    int i3 = base + 3 * blockDim.x;

    if (i3 < n4) {
        // Fast path: all four vectors valid. Loads issue back-to-back
        // (independent addresses) so 64B/thread is in flight before the
        // first dependent VALU+store.
        floatx4 a = __builtin_nontemporal_load(&x[i0]);
        floatx4 b = __builtin_nontemporal_load(&x[i1]);
        floatx4 c = __builtin_nontemporal_load(&x[i2]);
        floatx4 d = __builtin_nontemporal_load(&x[i3]);
        a += 42.0f;
        b += 42.0f;
        c += 42.0f;
        d += 42.0f;
        __builtin_nontemporal_store(a, &out[i0]);
        __builtin_nontemporal_store(b, &out[i1]);
        __builtin_nontemporal_store(c, &out[i2]);
        __builtin_nontemporal_store(d, &out[i3]);
    } else {
        // Tail (never taken for the 8192x4096 shape: n4 % 1024 == 0,
        // but keep it correct for any size).
        for (int i = i0; i < n4; i += blockDim.x) {
            floatx4 a = __builtin_nontemporal_load(&x[i]);
            a += 42.0f;
            __builtin_nontemporal_store(a, &out[i]);
        }
    }
}

extern "C" void kernel_launch(void* const* d_in, const int* in_sizes, int n_in,
                              void* d_out, int out_size, void* d_ws, size_t ws_size,
                              hipStream_t stream) {
    const floatx4* x = (const floatx4*)d_in[0];
    floatx4* out = (floatx4*)d_out;
    int n = in_sizes[0];              // 33,554,432 fp32
    int n4 = n >> 2;                  // 8,388,608 16B vectors
    int block = 256;
    int per_block = block * 4;        // 1024 vectors (16 KB) per block
    int grid = (n4 + per_block - 1) / per_block;  // 8,192 blocks
    add42_kernel<<<grid, block, 0, stream>>>(x, out, n4);
}